// Round 1
// baseline (133.459 us; speedup 1.0000x reference)
//
#include <hip/hip_runtime.h>
#include <hip/hip_bf16.h>

typedef __bf16 bf16x8 __attribute__((ext_vector_type(8)));
typedef float f32x4 __attribute__((ext_vector_type(4)));

#define B_SZ 64
#define L_SZ 1024
#define D_SZ 512

// ws layout (bytes):
//   [0,        524288)  Wt   : bf16 W_enc^T  [N=512][K=512]
//   [524288,   655360)  bias2p: f32 [64][512]  (attn2 + b_dec + b_enc)
//   [655360,   917504)  logits: f32 [64][1024]
//   [917504,  1966080)  part  : f32 [64][8][512]
#define WS_WT     0
#define WS_BIAS   524288
#define WS_LOGITS 655360
#define WS_PART   917504

__device__ __forceinline__ unsigned short f2bf(float f) {
    __bf16 h = (__bf16)f;
    return __builtin_bit_cast(unsigned short, h);
}

// K0a: Wt[n][k] = bf16(W_enc[k][n])
__global__ void k_wt(const float* __restrict__ W, unsigned short* __restrict__ Wt) {
    int n = blockIdx.x;
    for (int k = threadIdx.x; k < 512; k += 256)
        Wt[n * 512 + k] = f2bf(W[k * 512 + n]);
}

// K0b: bias2p[b][n] = dec[b]·W_dec[:,n] + b_dec[n] + b_enc[n]
__global__ void k_bias2(const float* __restrict__ dec, const float* __restrict__ Wd,
                        const float* __restrict__ b_dec, const float* __restrict__ b_enc,
                        float* __restrict__ bias2p) {
    int blk = blockIdx.x;           // 256 blocks: b = blk>>2, nc = blk&3
    int b = blk >> 2, nc = blk & 3;
    int t = threadIdx.x;
    __shared__ float sdec[512];
    __shared__ float red[256];
    for (int k = t; k < 512; k += 256) sdec[k] = dec[b * 512 + k];
    __syncthreads();
    int n = nc * 128 + (t & 127);
    int kh = t >> 7;                // 0 or 1
    float acc = 0.f;
    int k0 = kh * 256;
    #pragma unroll 4
    for (int k = k0; k < k0 + 256; ++k)
        acc += sdec[k] * Wd[k * 512 + n];
    red[t] = acc;
    __syncthreads();
    if (t < 128) {
        int nn = nc * 128 + t;
        bias2p[b * 512 + nn] = red[t] + red[t + 128] + b_dec[nn] + b_enc[nn];
    }
}

// K1: fused enc@W_enc + bias -> relu -> ·W_full  =>  logits [B,L]
__global__ __launch_bounds__(256) void k_logits(
        const float* __restrict__ enc, const unsigned short* __restrict__ Wt,
        const float* __restrict__ bias2p, const float* __restrict__ Wf,
        const float* __restrict__ bfull, float* __restrict__ logits) {
    __shared__ __align__(16) unsigned short lds[8192];  // 16 KB: 16 rows x 512 bf16, swizzled

    int t = threadIdx.x;
    int lane = t & 63;
    int w = t >> 6;                 // wave id 0..3
    int blk = blockIdx.x;           // 1024 blocks of 64 rows
    int row0 = blk * 64 + w * 16;   // this wave's 16-row tile
    int b = blk >> 4;               // 16 blocks per batch
    int m = lane & 15;              // A row within tile / D col
    int g = lane >> 4;              // k-subchunk 0..3

    // Load full-K A fragments for row (row0+m): A[f] covers k in [f*32, f*32+32)
    bf16x8 A[16];
    const float* ap = enc + (size_t)(row0 + m) * 512 + g * 8;
    #pragma unroll
    for (int f = 0; f < 16; ++f) {
        float4 x = *(const float4*)(ap + f * 32);
        float4 y = *(const float4*)(ap + f * 32 + 4);
        bf16x8 a;
        a[0] = (__bf16)x.x; a[1] = (__bf16)x.y; a[2] = (__bf16)x.z; a[3] = (__bf16)x.w;
        a[4] = (__bf16)y.x; a[5] = (__bf16)y.y; a[6] = (__bf16)y.z; a[7] = (__bf16)y.w;
        A[f] = a;
    }

    float p0 = 0.f, p1 = 0.f, p2 = 0.f, p3 = 0.f;
    int swz = (m & 7) << 4;         // read-side XOR swizzle (bytes)
    int rb = m * 1024;              // LDS row base (bytes), row stride 1 KB

    for (int nc = 0; nc < 32; ++nc) {
        int n0 = nc * 16;
        __syncthreads();            // previous iter's reads done before overwrite
        // stage Wt rows [n0, n0+16) into LDS, 16B units, XOR-swizzled by row&7
        #pragma unroll
        for (int q = 0; q < 4; ++q) {
            int u = t + 256 * q;    // 1024 units of 16B
            int r = u >> 6, c = u & 63;
            uint4 v = *(const uint4*)(Wt + (size_t)(n0 + r) * 512 + c * 8);
            int dst = r * 1024 + ((c * 16) ^ ((r & 7) << 4));
            *(uint4*)((char*)lds + dst) = v;
        }
        __syncthreads();

        f32x4 acc = {0.f, 0.f, 0.f, 0.f};
        #pragma unroll
        for (int f = 0; f < 16; ++f) {
            int kb = f * 64 + g * 16;   // byte offset of this lane's 8 bf16 in the row
            uint4 raw = *(const uint4*)((const char*)lds + rb + (kb ^ swz));
            bf16x8 bf = __builtin_bit_cast(bf16x8, raw);
            acc = __builtin_amdgcn_mfma_f32_16x16x32_bf16(A[f], bf, acc, 0, 0, 0);
        }
        // D mapping: col = lane&15 (= n0+m), row = g*4 + reg
        int col = n0 + m;
        float bias = bias2p[b * 512 + col];
        float wf = Wf[col];
        float v0 = acc[0] + bias; v0 = v0 > 0.f ? v0 : 0.f; p0 += v0 * wf;
        float v1 = acc[1] + bias; v1 = v1 > 0.f ? v1 : 0.f; p1 += v1 * wf;
        float v2 = acc[2] + bias; v2 = v2 > 0.f ? v2 : 0.f; p2 += v2 * wf;
        float v3 = acc[3] + bias; v3 = v3 > 0.f ? v3 : 0.f; p3 += v3 * wf;
    }

    // reduce over the 16 cols (lanes sharing lane>>4)
    float p[4] = {p0, p1, p2, p3};
    #pragma unroll
    for (int r = 0; r < 4; ++r) {
        float v = p[r];
        v += __shfl_xor(v, 1, 64);
        v += __shfl_xor(v, 2, 64);
        v += __shfl_xor(v, 4, 64);
        v += __shfl_xor(v, 8, 64);
        p[r] = v;
    }
    if (m == 0) {
        float bf0 = bfull[0];
        #pragma unroll
        for (int r = 0; r < 4; ++r)
            logits[row0 + g * 4 + r] = p[r] + bf0;
    }
}

// K2: softmax over L per batch; writes alpha straight into d_out region
__global__ void k_softmax(const float* __restrict__ logits, float* __restrict__ alpha) {
    int b = blockIdx.x;
    int t = threadIdx.x;
    __shared__ float red[256];
    float4 v = ((const float4*)(logits + b * 1024))[t];
    float mx = fmaxf(fmaxf(v.x, v.y), fmaxf(v.z, v.w));
    red[t] = mx;
    __syncthreads();
    for (int s = 128; s > 0; s >>= 1) {
        if (t < s) red[t] = fmaxf(red[t], red[t + s]);
        __syncthreads();
    }
    mx = red[0];
    __syncthreads();
    float4 e;
    e.x = expf(v.x - mx); e.y = expf(v.y - mx);
    e.z = expf(v.z - mx); e.w = expf(v.w - mx);
    red[t] = e.x + e.y + e.z + e.w;
    __syncthreads();
    for (int s = 128; s > 0; s >>= 1) {
        if (t < s) red[t] += red[t + s];
        __syncthreads();
    }
    float inv = 1.0f / red[0];
    float4 o;
    o.x = e.x * inv; o.y = e.y * inv; o.z = e.z * inv; o.w = e.w * inv;
    ((float4*)(alpha + b * 1024))[t] = o;
}

// K3: partial weighted sums over l-chunks of 128
__global__ void k_wsum_part(const float* __restrict__ enc, const float* __restrict__ alpha,
                            float* __restrict__ part) {
    int blk = blockIdx.x;           // 512 blocks: b = blk>>3, chunk c = blk&7
    int b = blk >> 3, c = blk & 7;
    int t = threadIdx.x;
    const float* ep = enc + (size_t)(b * 1024 + c * 128) * 512;
    const float* al = alpha + b * 1024 + c * 128;
    float ax = 0.f, ay = 0.f;
    #pragma unroll 4
    for (int l = 0; l < 128; ++l) {
        float a = al[l];
        float2 e = *(const float2*)(ep + (size_t)l * 512 + t * 2);
        ax += e.x * a;
        ay += e.y * a;
    }
    float* pp = part + (size_t)blk * 512;
    pp[t * 2] = ax;
    pp[t * 2 + 1] = ay;
}

// K4: reduce 8 partials -> attn_weighted_enc
__global__ void k_wsum_final(const float* __restrict__ part, float* __restrict__ out) {
    int b = blockIdx.x;
    int t = threadIdx.x;
    float sx = 0.f, sy = 0.f;
    #pragma unroll
    for (int c = 0; c < 8; ++c) {
        float2 v = *(const float2*)(part + (size_t)(b * 8 + c) * 512 + t * 2);
        sx += v.x;
        sy += v.y;
    }
    float2 o; o.x = sx; o.y = sy;
    *(float2*)(out + b * 512 + t * 2) = o;
}

extern "C" void kernel_launch(void* const* d_in, const int* in_sizes, int n_in,
                              void* d_out, int out_size, void* d_ws, size_t ws_size,
                              hipStream_t stream) {
    const float* enc    = (const float*)d_in[0];  // [64,1024,512]
    const float* dec    = (const float*)d_in[1];  // [64,512]
    const float* W_enc  = (const float*)d_in[2];  // [512,512]
    const float* b_enc  = (const float*)d_in[3];  // [512]
    const float* W_dec  = (const float*)d_in[4];  // [512,512]
    const float* b_dec  = (const float*)d_in[5];  // [512]
    const float* W_full = (const float*)d_in[6];  // [512]
    const float* b_full = (const float*)d_in[7];  // scalar

    float* out = (float*)d_out;                   // [0,32768) weighted enc; [32768,98304) alpha
    char* ws = (char*)d_ws;
    unsigned short* Wt = (unsigned short*)(ws + WS_WT);
    float* bias2p = (float*)(ws + WS_BIAS);
    float* logits = (float*)(ws + WS_LOGITS);
    float* part   = (float*)(ws + WS_PART);
    float* alpha  = out + 32768;

    hipLaunchKernelGGL(k_wt,         dim3(512), dim3(256), 0, stream, W_enc, Wt);
    hipLaunchKernelGGL(k_bias2,      dim3(256), dim3(256), 0, stream, dec, W_dec, b_dec, b_enc, bias2p);
    hipLaunchKernelGGL(k_logits,     dim3(1024), dim3(256), 0, stream, enc, Wt, bias2p, W_full, b_full, logits);
    hipLaunchKernelGGL(k_softmax,    dim3(64),  dim3(256), 0, stream, logits, alpha);
    hipLaunchKernelGGL(k_wsum_part,  dim3(512), dim3(256), 0, stream, enc, alpha, part);
    hipLaunchKernelGGL(k_wsum_final, dim3(64),  dim3(256), 0, stream, part, out);
}

// Round 2
// 109.599 us; speedup vs baseline: 1.2177x; 1.2177x over previous
//
#include <hip/hip_runtime.h>
#include <hip/hip_bf16.h>

typedef __bf16 bf16x8 __attribute__((ext_vector_type(8)));
typedef float f32x4 __attribute__((ext_vector_type(4)));
typedef unsigned int u32;

#define B_SZ 64
#define L_SZ 1024
#define D_SZ 512

// ws layout (bytes):
//   [0,        524288)  Wt    : bf16 W_enc^T  [N=512][K=512]
//   [524288,   655360)  bias2p: f32 [64][512]  (attn2 + b_dec + b_enc)
//   [655360,   917504)  logits: f32 [64][1024]
//   [917504,  1966080)  part  : f32 [64][8][512]
#define WS_WT     0
#define WS_BIAS   524288
#define WS_LOGITS 655360
#define WS_PART   917504

__device__ __forceinline__ unsigned short f2bf(float f) {
    __bf16 h = (__bf16)f;
    return __builtin_bit_cast(unsigned short, h);
}

__device__ __forceinline__ void gload_lds16(const void* g, void* l) {
    __builtin_amdgcn_global_load_lds(
        (const __attribute__((address_space(1))) u32*)g,
        (__attribute__((address_space(3))) u32*)l, 16, 0, 0);
}

// K0a: Wt[n][k] = bf16(W_enc[k][n])
__global__ void k_wt(const float* __restrict__ W, unsigned short* __restrict__ Wt) {
    int n = blockIdx.x;
    for (int k = threadIdx.x; k < 512; k += 256)
        Wt[n * 512 + k] = f2bf(W[k * 512 + n]);
}

// K0b: bias2p[b][n] = dec[b]·W_dec[:,n] + b_dec[n] + b_enc[n]
__global__ void k_bias2(const float* __restrict__ dec, const float* __restrict__ Wd,
                        const float* __restrict__ b_dec, const float* __restrict__ b_enc,
                        float* __restrict__ bias2p) {
    int blk = blockIdx.x;           // 256 blocks: b = blk>>2, nc = blk&3
    int b = blk >> 2, nc = blk & 3;
    int t = threadIdx.x;
    __shared__ float sdec[512];
    __shared__ float red[256];
    for (int k = t; k < 512; k += 256) sdec[k] = dec[b * 512 + k];
    __syncthreads();
    int n = nc * 128 + (t & 127);
    int kh = t >> 7;                // 0 or 1
    float acc = 0.f;
    int k0 = kh * 256;
    #pragma unroll 4
    for (int k = k0; k < k0 + 256; ++k)
        acc += sdec[k] * Wd[k * 512 + n];
    red[t] = acc;
    __syncthreads();
    if (t < 128) {
        int nn = nc * 128 + t;
        bias2p[b * 512 + nn] = red[t] + red[t + 128] + b_dec[nn] + b_enc[nn];
    }
}

// K1: fused enc@W_enc + bias -> relu -> ·W_full  =>  logits [B,L]
// 512 blocks x 256 thr. Block = 128 rows; wave = 32 rows (two 16-row A tiles,
// full K in registers). B streamed through dbuf LDS via global_load_lds with
// pre-swizzled source; XOR(m<<4) conflict-free ds_read_b128.
__global__ __launch_bounds__(256, 2) void k_logits(
        const float* __restrict__ enc, const unsigned short* __restrict__ Wt,
        const float* __restrict__ bias2p, const float* __restrict__ Wf,
        const float* __restrict__ bfull, float* __restrict__ logits) {
    __shared__ __align__(16) unsigned short lds[2][8192];  // 2 x 16 KB

    int t = threadIdx.x;
    int lane = t & 63;
    int w = t >> 6;                 // wave id 0..3
    int blk = blockIdx.x;           // 512 blocks of 128 rows
    int rows0 = blk * 128;
    int b = blk >> 3;               // 8 blocks per batch
    int m = lane & 15;              // A row within tile / D col
    int g = lane >> 4;              // k-subgroup 0..3

    // Full-K A fragments for two 16-row tiles: rows0 + w*32 + T*16 + m
    bf16x8 A0[16], A1[16];
    {
        const float* ap0 = enc + (size_t)(rows0 + w * 32 + m) * 512 + g * 8;
        const float* ap1 = ap0 + 16 * 512;
        #pragma unroll
        for (int f = 0; f < 16; ++f) {
            float4 x = *(const float4*)(ap0 + f * 32);
            float4 y = *(const float4*)(ap0 + f * 32 + 4);
            bf16x8 a;
            a[0] = (__bf16)x.x; a[1] = (__bf16)x.y; a[2] = (__bf16)x.z; a[3] = (__bf16)x.w;
            a[4] = (__bf16)y.x; a[5] = (__bf16)y.y; a[6] = (__bf16)y.z; a[7] = (__bf16)y.w;
            A0[f] = a;
            float4 x1 = *(const float4*)(ap1 + f * 32);
            float4 y1 = *(const float4*)(ap1 + f * 32 + 4);
            bf16x8 a1;
            a1[0] = (__bf16)x1.x; a1[1] = (__bf16)x1.y; a1[2] = (__bf16)x1.z; a1[3] = (__bf16)x1.w;
            a1[4] = (__bf16)y1.x; a1[5] = (__bf16)y1.y; a1[6] = (__bf16)y1.z; a1[7] = (__bf16)y1.w;
            A1[f] = a1;
        }
    }

    // stage chunk nc into lds[buf]: 16 rows x 1KB; wave w does rows w*4..w*4+3.
    // linear LDS dest (global_load_lds), source 16B-unit pre-swizzled: u' = lane ^ r
    #define STAGE(bufi, nc_)                                                      \
        {                                                                         \
            int n0_ = (nc_) * 16;                                                 \
            _Pragma("unroll")                                                     \
            for (int j = 0; j < 4; ++j) {                                         \
                int r_ = w * 4 + j;                                               \
                const char* src_ = (const char*)Wt + (size_t)(n0_ + r_) * 1024    \
                                   + ((lane ^ r_) << 4);                          \
                char* dst_ = (char*)&lds[bufi][0] + r_ * 1024;                    \
                gload_lds16(src_, dst_);                                          \
            }                                                                     \
        }

    STAGE(0, 0)
    __syncthreads();   // drains A loads + stage of chunk 0

    float p0[4] = {0.f, 0.f, 0.f, 0.f};
    float p1[4] = {0.f, 0.f, 0.f, 0.f};
    int buf = 0;
    int rbase = m * 1024;
    int swz = m << 4;

    for (int nc = 0; nc < 32; ++nc) {
        if (nc < 31) {
            if (buf) STAGE(0, nc + 1) else STAGE(1, nc + 1)
        }
        const char* base = (const char*)&lds[buf][0] + rbase;
        f32x4 acc0 = {0.f, 0.f, 0.f, 0.f};
        f32x4 acc1 = {0.f, 0.f, 0.f, 0.f};
        #pragma unroll
        for (int f = 0; f < 16; ++f) {
            uint4 raw = *(const uint4*)(base + ((f * 64 + g * 16) ^ swz));
            bf16x8 bfr = __builtin_bit_cast(bf16x8, raw);
            acc0 = __builtin_amdgcn_mfma_f32_16x16x32_bf16(A0[f], bfr, acc0, 0, 0, 0);
            acc1 = __builtin_amdgcn_mfma_f32_16x16x32_bf16(A1[f], bfr, acc1, 0, 0, 0);
        }
        int col = nc * 16 + m;
        float bias = bias2p[b * 512 + col];
        float wf = Wf[col];
        #pragma unroll
        for (int r = 0; r < 4; ++r) {
            float v0 = acc0[r] + bias; v0 = v0 > 0.f ? v0 : 0.f; p0[r] += v0 * wf;
            float v1 = acc1[r] + bias; v1 = v1 > 0.f ? v1 : 0.f; p1[r] += v1 * wf;
        }
        __syncthreads();             // stage(nc+1) complete + all reads of buf done
        buf ^= 1;
    }

    // reduce over the 16 cols (lanes varying in m, same g)
    float bf0 = bfull[0];
    #pragma unroll
    for (int r = 0; r < 4; ++r) {
        float v = p0[r];
        v += __shfl_xor(v, 1, 64);
        v += __shfl_xor(v, 2, 64);
        v += __shfl_xor(v, 4, 64);
        v += __shfl_xor(v, 8, 64);
        if (m == 0) logits[rows0 + w * 32 + g * 4 + r] = v + bf0;
        float u = p1[r];
        u += __shfl_xor(u, 1, 64);
        u += __shfl_xor(u, 2, 64);
        u += __shfl_xor(u, 4, 64);
        u += __shfl_xor(u, 8, 64);
        if (m == 0) logits[rows0 + w * 32 + 16 + g * 4 + r] = u + bf0;
    }
}

// K2: softmax over L per batch; writes alpha straight into d_out region
__global__ void k_softmax(const float* __restrict__ logits, float* __restrict__ alpha) {
    int b = blockIdx.x;
    int t = threadIdx.x;
    __shared__ float red[256];
    float4 v = ((const float4*)(logits + b * 1024))[t];
    float mx = fmaxf(fmaxf(v.x, v.y), fmaxf(v.z, v.w));
    red[t] = mx;
    __syncthreads();
    for (int s = 128; s > 0; s >>= 1) {
        if (t < s) red[t] = fmaxf(red[t], red[t + s]);
        __syncthreads();
    }
    mx = red[0];
    __syncthreads();
    float4 e;
    e.x = expf(v.x - mx); e.y = expf(v.y - mx);
    e.z = expf(v.z - mx); e.w = expf(v.w - mx);
    red[t] = e.x + e.y + e.z + e.w;
    __syncthreads();
    for (int s = 128; s > 0; s >>= 1) {
        if (t < s) red[t] += red[t + s];
        __syncthreads();
    }
    float inv = 1.0f / red[0];
    float4 o;
    o.x = e.x * inv; o.y = e.y * inv; o.z = e.z * inv; o.w = e.w * inv;
    ((float4*)(alpha + b * 1024))[t] = o;
}

// K3: partial weighted sums over l-chunks of 128
__global__ void k_wsum_part(const float* __restrict__ enc, const float* __restrict__ alpha,
                            float* __restrict__ part) {
    int blk = blockIdx.x;           // 512 blocks: b = blk>>3, chunk c = blk&7
    int b = blk >> 3, c = blk & 7;
    int t = threadIdx.x;
    const float* ep = enc + (size_t)(b * 1024 + c * 128) * 512;
    const float* al = alpha + b * 1024 + c * 128;
    float ax = 0.f, ay = 0.f;
    #pragma unroll 4
    for (int l = 0; l < 128; ++l) {
        float a = al[l];
        float2 e = *(const float2*)(ep + (size_t)l * 512 + t * 2);
        ax += e.x * a;
        ay += e.y * a;
    }
    float* pp = part + (size_t)blk * 512;
    pp[t * 2] = ax;
    pp[t * 2 + 1] = ay;
}

// K4: reduce 8 partials -> attn_weighted_enc
__global__ void k_wsum_final(const float* __restrict__ part, float* __restrict__ out) {
    int b = blockIdx.x;
    int t = threadIdx.x;
    float sx = 0.f, sy = 0.f;
    #pragma unroll
    for (int c = 0; c < 8; ++c) {
        float2 v = *(const float2*)(part + (size_t)(b * 8 + c) * 512 + t * 2);
        sx += v.x;
        sy += v.y;
    }
    float2 o; o.x = sx; o.y = sy;
    *(float2*)(out + b * 512 + t * 2) = o;
}

extern "C" void kernel_launch(void* const* d_in, const int* in_sizes, int n_in,
                              void* d_out, int out_size, void* d_ws, size_t ws_size,
                              hipStream_t stream) {
    const float* enc    = (const float*)d_in[0];  // [64,1024,512]
    const float* dec    = (const float*)d_in[1];  // [64,512]
    const float* W_enc  = (const float*)d_in[2];  // [512,512]
    const float* b_enc  = (const float*)d_in[3];  // [512]
    const float* W_dec  = (const float*)d_in[4];  // [512,512]
    const float* b_dec  = (const float*)d_in[5];  // [512]
    const float* W_full = (const float*)d_in[6];  // [512]
    const float* b_full = (const float*)d_in[7];  // scalar

    float* out = (float*)d_out;                   // [0,32768) weighted enc; [32768,98304) alpha
    char* ws = (char*)d_ws;
    unsigned short* Wt = (unsigned short*)(ws + WS_WT);
    float* bias2p = (float*)(ws + WS_BIAS);
    float* logits = (float*)(ws + WS_LOGITS);
    float* part   = (float*)(ws + WS_PART);
    float* alpha  = out + 32768;

    hipLaunchKernelGGL(k_wt,         dim3(512), dim3(256), 0, stream, W_enc, Wt);
    hipLaunchKernelGGL(k_bias2,      dim3(256), dim3(256), 0, stream, dec, W_dec, b_dec, b_enc, bias2p);
    hipLaunchKernelGGL(k_logits,     dim3(512), dim3(256), 0, stream, enc, Wt, bias2p, W_full, b_full, logits);
    hipLaunchKernelGGL(k_softmax,    dim3(64),  dim3(256), 0, stream, logits, alpha);
    hipLaunchKernelGGL(k_wsum_part,  dim3(512), dim3(256), 0, stream, enc, alpha, part);
    hipLaunchKernelGGL(k_wsum_final, dim3(64),  dim3(256), 0, stream, part, out);
}